// Round 1
// baseline (152.027 us; speedup 1.0000x reference)
//
#include <hip/hip_runtime.h>
#include <hip/hip_bf16.h>
#include <stdint.h>

#define B_   4
#define S_   1024
#define HID_ 1024
#define H_   16
#define DH_  64

typedef short bf16x8 __attribute__((ext_vector_type(8)));
typedef float f32x4  __attribute__((ext_vector_type(4)));
typedef unsigned int u32;
typedef unsigned short u16;

typedef u32 __attribute__((address_space(1))) as1_u32;
typedef u32 __attribute__((address_space(3))) as3_u32;

__device__ __forceinline__ f32x4 mfma16(bf16x8 a, bf16x8 b, f32x4 c) {
  return __builtin_amdgcn_mfma_f32_16x16x32_bf16(a, b, c, 0, 0, 0);
}

// async global->LDS, 16B per lane; lds ptr must be wave-uniform base
__device__ __forceinline__ void gload16(const void* g, void* l) {
  __builtin_amdgcn_global_load_lds((const as1_u32*)g, (as3_u32*)l, 16, 0, 0);
}

__device__ __forceinline__ u16 f2bf(float f) {
  __hip_bfloat16 h = __float2bfloat16(f);
  union { __hip_bfloat16 h; u16 u; } cv; cv.h = h; return cv.u;
}

// ---------------- converts ----------------
__global__ __launch_bounds__(256) void cvt_acts(const float* a0, const float* a1,
                                                const float* a2, const float* a3,
                                                u16* d0, u16* d1, u16* d2, u16* d3) {
  int t = blockIdx.x * 256 + threadIdx.x;      // 2M threads, 8 elems each
  int sel = t >> 19;                           // 524288 threads per 4M tensor
  size_t i = (size_t)(t & 524287) * 8;
  const float* s; u16* d;
  if (sel == 0)      { s = a0; d = d0; }
  else if (sel == 1) { s = a1; d = d1; }
  else if (sel == 2) { s = a2; d = d2; }
  else               { s = a3; d = d3; }
  float4 v0 = *(const float4*)(s + i);
  float4 v1 = *(const float4*)(s + i + 4);
  uint4 r;
  r.x = (u32)f2bf(v0.x) | ((u32)f2bf(v0.y) << 16);
  r.y = (u32)f2bf(v0.z) | ((u32)f2bf(v0.w) << 16);
  r.z = (u32)f2bf(v1.x) | ((u32)f2bf(v1.y) << 16);
  r.w = (u32)f2bf(v1.z) | ((u32)f2bf(v1.w) << 16);
  *(uint4*)(d + i) = r;
}

__global__ __launch_bounds__(256) void cvt_wts(const float* a0, const float* a1,
                                               const float* a2, const float* a3, const float* a4,
                                               u16* d0, u16* d1, u16* d2, u16* d3, u16* d4) {
  int t = blockIdx.x * 256 + threadIdx.x;      // 655360 threads
  int sel = t >> 17;                           // 131072 threads per 1M tensor
  size_t i = (size_t)(t & 131071) * 8;
  const float* s; u16* d;
  if (sel == 0)      { s = a0; d = d0; }
  else if (sel == 1) { s = a1; d = d1; }
  else if (sel == 2) { s = a2; d = d2; }
  else if (sel == 3) { s = a3; d = d3; }
  else               { s = a4; d = d4; }
  float4 v0 = *(const float4*)(s + i);
  float4 v1 = *(const float4*)(s + i + 4);
  uint4 r;
  r.x = (u32)f2bf(v0.x) | ((u32)f2bf(v0.y) << 16);
  r.y = (u32)f2bf(v0.z) | ((u32)f2bf(v0.w) << 16);
  r.z = (u32)f2bf(v1.x) | ((u32)f2bf(v1.y) << 16);
  r.w = (u32)f2bf(v1.z) | ((u32)f2bf(v1.w) << 16);
  *(uint4*)(d + i) = r;
}

__global__ __launch_bounds__(256) void mk_madd(const int* mask, float* madd) {
  int t = blockIdx.x * 256 + threadIdx.x;      // 4096
  madd[t] = (mask[t] == 0) ? -1e9f : 0.0f;
}

// ---------------- NT GEMM: C[M,N] = sum_k A[m,k]*W[n,k] (+bias) ----------------
// M=4096, N=1024, K=1024 (PAIRS=2: two (A,W) pairs accumulated -> K=2048 effective)
// tile 128x64, BK=64, 256 threads (4 waves as 2x2, each wave 64x32)
// LDS tiles staged via global_load_lds with XOR-swizzled SOURCE so ds_read_b128 is conflict-free.
// OMODE 0: bf16 row-major; 1: bf16 transposed Vt[bh][dh][s]; 2: f32 row-major
template<int PAIRS, int OMODE>
__global__ __launch_bounds__(256) void gemm_nt(const u16* __restrict__ A0, const u16* __restrict__ W0,
                                               const u16* __restrict__ A1, const u16* __restrict__ W1,
                                               const float* __restrict__ bias0, const float* __restrict__ bias1,
                                               void* __restrict__ outp) {
  __shared__ __align__(16) char smem[24576];   // A tile 16KB @0, W tile 8KB @16384
  const int tid = threadIdx.x;
  const int lane = tid & 63, w = tid >> 6;
  const int g = lane >> 4, ql = lane & 15;
  const int wm = w >> 1, wn = w & 1;
  const int bid = blockIdx.x;
  const int m0 = (bid >> 4) * 128;
  const int n0 = (bid & 15) * 64;
  const int xr = ql & 7;

  f32x4 acc[4][2];
  #pragma unroll
  for (int mi = 0; mi < 4; ++mi)
    #pragma unroll
    for (int ni = 0; ni < 2; ++ni) acc[mi][ni] = f32x4{0.f, 0.f, 0.f, 0.f};

  for (int kt = 0; kt < 16 * PAIRS; ++kt) {
    const u16* As = (PAIRS == 2 && kt >= 16) ? A1 : A0;
    const u16* Ws = (PAIRS == 2 && kt >= 16) ? W1 : W0;
    const int kk = (kt & 15) * 64;
    #pragma unroll
    for (int is = 0; is < 4; ++is) {           // A tile: 16KB
      int o = is * 4096 + tid * 16;
      int row = o >> 7, ch = (o >> 4) & 7;
      gload16(As + (size_t)(m0 + row) * HID_ + kk + ((ch ^ (row & 7)) * 8),
              smem + is * 4096 + w * 1024);
    }
    #pragma unroll
    for (int is = 0; is < 2; ++is) {           // W tile: 8KB
      int o = is * 4096 + tid * 16;
      int row = o >> 7, ch = (o >> 4) & 7;
      gload16(Ws + (size_t)(n0 + row) * HID_ + kk + ((ch ^ (row & 7)) * 8),
              smem + 16384 + is * 4096 + w * 1024);
    }
    __syncthreads();

    bf16x8 af[4][2], bfv[2][2];
    #pragma unroll
    for (int mi = 0; mi < 4; ++mi)
      #pragma unroll
      for (int c = 0; c < 2; ++c) {
        int row = wm * 64 + mi * 16 + ql;
        af[mi][c] = *(const bf16x8*)(smem + row * 128 + (((c * 4 + g) ^ xr) * 16));
      }
    #pragma unroll
    for (int ni = 0; ni < 2; ++ni)
      #pragma unroll
      for (int c = 0; c < 2; ++c) {
        int row = wn * 32 + ni * 16 + ql;
        bfv[ni][c] = *(const bf16x8*)(smem + 16384 + row * 128 + (((c * 4 + g) ^ xr) * 16));
      }
    #pragma unroll
    for (int c = 0; c < 2; ++c)
      #pragma unroll
      for (int mi = 0; mi < 4; ++mi)
        #pragma unroll
        for (int ni = 0; ni < 2; ++ni)
          acc[mi][ni] = mfma16(af[mi][c], bfv[ni][c], acc[mi][ni]);
    __syncthreads();
  }

  #pragma unroll
  for (int ni = 0; ni < 2; ++ni) {
    int n = n0 + wn * 32 + ni * 16 + ql;
    float bs = bias0[n];
    if (PAIRS == 2) bs += bias1[n];
    #pragma unroll
    for (int mi = 0; mi < 4; ++mi) {
      #pragma unroll
      for (int i = 0; i < 4; ++i) {
        int m = m0 + wm * 64 + mi * 16 + g * 4 + i;   // D: row=(lane>>4)*4+i, col=lane&15
        float v = acc[mi][ni][i] + bs;
        if (OMODE == 0) {
          ((u16*)outp)[(size_t)m * HID_ + n] = f2bf(v);
        } else if (OMODE == 1) {
          int b = m >> 10, s = m & 1023;
          int h = n >> 6, dh = n & 63;
          ((u16*)outp)[(((size_t)((b * H_ + h) * DH_ + dh)) << 10) + s] = f2bf(v);
        } else {
          ((float*)outp)[(size_t)m * HID_ + n] = v;
        }
      }
    }
  }
}

// ---------------- flash attention ----------------
// grid: 1024 = (bh 64) x (qtile 16); 256 threads = 4 waves x 16 q-rows.
// Swapped QK^T: S^T = K·Q^T so each lane's 16 scores belong to ONE q-row (q = lane&15).
// PV: out^T = Vt·P^T ; P^T B-frags built in-register via packed-bf16 shuffles.
__global__ __launch_bounds__(256) void attn(const u16* __restrict__ Qp, const u16* __restrict__ KKp,
                                            const u16* __restrict__ Vt, const float* __restrict__ madd_g,
                                            u16* __restrict__ hidden) {
  __shared__ __align__(16) char smem[20480];   // K 8KB @0, Vt 8KB @8192, madd 4KB @16384
  const int tid = threadIdx.x;
  const int lane = tid & 63, w = tid >> 6;
  const int g = lane >> 4, ql = lane & 15;
  const int bid = blockIdx.x;
  const int qt = bid & 15, bh = bid >> 4;
  const int b = bh >> 4, h = bh & 15;
  const int q0 = qt * 64;
  const int xr = ql & 7;
  const float scale = 0.07216878364870322f;    // 1/sqrt(3*DH)

  ((float4*)(smem + 16384))[tid] = ((const float4*)(madd_g + b * S_))[tid];

  const u16* qrow = Qp + (size_t)(b * S_ + q0 + w * 16 + ql) * HID_ + h * DH_;
  bf16x8 qb0 = *(const bf16x8*)(qrow + g * 8);        // B-frag kchunk 0 (dh 0..31)
  bf16x8 qb1 = *(const bf16x8*)(qrow + 32 + g * 8);   // kchunk 1 (dh 32..63)

  f32x4 oacc[4];
  #pragma unroll
  for (int d = 0; d < 4; ++d) oacc[d] = f32x4{0.f, 0.f, 0.f, 0.f};
  float m_run = -1e30f, l_run = 0.f;

  __syncthreads();

  for (int it = 0; it < 16; ++it) {
    const int k0 = it * 64;
    #pragma unroll
    for (int is = 0; is < 2; ++is) {
      int o = is * 4096 + tid * 16;
      int row = o >> 7, ch = (o >> 4) & 7;
      gload16(KKp + (size_t)(b * S_ + k0 + row) * HID_ + h * DH_ + ((ch ^ (row & 7)) * 8),
              smem + is * 4096 + w * 1024);
      gload16(Vt + (size_t)(bh * DH_ + row) * S_ + k0 + ((ch ^ (row & 7)) * 8),
              smem + 8192 + is * 4096 + w * 1024);
    }
    __syncthreads();

    // QK^T (swapped): tile t rows = keys 16t..16t+15; lane holds key 16t+4g+i, q=ql
    float sv[4][4];
    #pragma unroll
    for (int t = 0; t < 4; ++t) {
      const char* krow = smem + (16 * t + ql) * 128;
      bf16x8 ka0 = *(const bf16x8*)(krow + ((g ^ xr) * 16));
      bf16x8 ka1 = *(const bf16x8*)(krow + (((4 + g) ^ xr) * 16));
      f32x4 st = mfma16(ka0, qb0, f32x4{0.f, 0.f, 0.f, 0.f});
      st = mfma16(ka1, qb1, st);
      f32x4 md = *(const f32x4*)(smem + 16384 + (k0 + 16 * t + 4 * g) * 4);
      #pragma unroll
      for (int i = 0; i < 4; ++i) sv[t][i] = st[i] * scale + md[i];
    }
    // online softmax: row q=ql spread over 4 lane-groups -> shfl_xor 16,32
    float mloc = sv[0][0];
    #pragma unroll
    for (int t = 0; t < 4; ++t)
      #pragma unroll
      for (int i = 0; i < 4; ++i) mloc = fmaxf(mloc, sv[t][i]);
    mloc = fmaxf(mloc, __shfl_xor(mloc, 16, 64));
    mloc = fmaxf(mloc, __shfl_xor(mloc, 32, 64));
    float mnew = fmaxf(m_run, mloc);
    float alpha = __expf(m_run - mnew);
    float pvs[4][4];
    float rsum = 0.f;
    #pragma unroll
    for (int t = 0; t < 4; ++t)
      #pragma unroll
      for (int i = 0; i < 4; ++i) { float p = __expf(sv[t][i] - mnew); pvs[t][i] = p; rsum += p; }
    rsum += __shfl_xor(rsum, 16, 64);
    rsum += __shfl_xor(rsum, 32, 64);
    l_run = l_run * alpha + rsum;
    m_run = mnew;
    #pragma unroll
    for (int d = 0; d < 4; ++d) oacc[d] *= alpha;

    // pack P to bf16 pairs: pk[u][t] = (p[t][2u+1]<<16)|p[t][2u]
    u32 pk[2][4];
    #pragma unroll
    for (int t = 0; t < 4; ++t) {
      pk[0][t] = (u32)f2bf(pvs[t][0]) | ((u32)f2bf(pvs[t][1]) << 16);
      pk[1][t] = (u32)f2bf(pvs[t][2]) | ((u32)f2bf(pvs[t][3]) << 16);
    }
    // B-frag for PV kchunk c: lane needs P^T[32c+8g+j][ql], j=0..7
    // source lane = (2(g&1)+(jp>>1))*16+ql, reg t = 2c+(g>>1) (dest-side select), u = jp&1
    const int srcbase = (2 * (g & 1)) * 16 + ql;
    const bool hi = (g >> 1) != 0;
    #pragma unroll
    for (int c = 0; c < 2; ++c) {
      u32 pb[4];
      #pragma unroll
      for (int jp = 0; jp < 4; ++jp) {
        int src = srcbase + (jp >> 1) * 16;
        u32 v0 = (u32)__shfl((int)pk[jp & 1][2 * c], src, 64);
        u32 v1 = (u32)__shfl((int)pk[jp & 1][2 * c + 1], src, 64);
        pb[jp] = hi ? v1 : v0;
      }
      union { u32 u[4]; bf16x8 v; } pu;
      pu.u[0] = pb[0]; pu.u[1] = pb[1]; pu.u[2] = pb[2]; pu.u[3] = pb[3];
      #pragma unroll
      for (int d = 0; d < 4; ++d) {
        const char* vrow = smem + 8192 + (16 * d + ql) * 128;
        bf16x8 va = *(const bf16x8*)(vrow + (((c * 4 + g) ^ xr) * 16));
        oacc[d] = mfma16(va, pu.v, oacc[d]);     // out^T[dh][q]
      }
    }
    __syncthreads();
  }

  // epilogue: divide, transpose via LDS (per-wave region), coalesced bf16 write
  float inv = 1.0f / l_run;
  char* ep = smem + w * 2304;                    // 16 rows x 144B (64 bf16 + pad)
  #pragma unroll
  for (int d = 0; d < 4; ++d)
    #pragma unroll
    for (int i = 0; i < 4; ++i)
      *(u16*)(ep + ql * 144 + (16 * d + 4 * g + i) * 2) = f2bf(oacc[d][i] * inv);
  __syncthreads();
  int r = lane >> 2, cc = lane & 3;
  const char* erow = smem + w * 2304 + r * 144 + cc * 32;
  uint4 v0 = *(const uint4*)erow;
  uint4 v1 = *(const uint4*)(erow + 16);
  u16* orow = hidden + (size_t)(b * S_ + q0 + w * 16 + r) * HID_ + h * DH_ + cc * 16;
  *(uint4*)orow = v0;
  *(uint4*)(orow + 8) = v1;
}

// ---------------- launch ----------------
extern "C" void kernel_launch(void* const* d_in, const int* in_sizes, int n_in,
                              void* d_out, int out_size, void* d_ws, size_t ws_size,
                              hipStream_t stream) {
  (void)in_sizes; (void)n_in; (void)out_size; (void)ws_size;
  const float* q    = (const float*)d_in[0];
  const float* k    = (const float*)d_in[1];
  const float* v    = (const float*)d_in[2];
  const float* kb   = (const float*)d_in[3];
  const int*   mask = (const int*)  d_in[4];
  const float* Wq   = (const float*)d_in[5];
  const float* bq   = (const float*)d_in[6];
  const float* Wk   = (const float*)d_in[7];
  const float* bk   = (const float*)d_in[8];
  const float* Wv   = (const float*)d_in[9];
  const float* bv   = (const float*)d_in[10];
  const float* Wkb  = (const float*)d_in[11];
  const float* bkb  = (const float*)d_in[12];
  const float* Wo   = (const float*)d_in[13];
  const float* bo   = (const float*)d_in[14];

  char* ws = (char*)d_ws;
  const size_t MB = 1024 * 1024;
  u16* qbf   = (u16*)(ws + 0 * MB);
  u16* kbf   = (u16*)(ws + 8 * MB);
  u16* vbf   = (u16*)(ws + 16 * MB);
  u16* kbbf  = (u16*)(ws + 24 * MB);
  u16* Wqbf  = (u16*)(ws + 32 * MB);
  u16* Wkbf  = (u16*)(ws + 34 * MB);
  u16* Wvbf  = (u16*)(ws + 36 * MB);
  u16* Wkbbf = (u16*)(ws + 38 * MB);
  u16* Wobf  = (u16*)(ws + 40 * MB);
  u16* Qp    = (u16*)(ws + 42 * MB);
  u16* KKp   = (u16*)(ws + 50 * MB);
  u16* Vtp   = (u16*)(ws + 58 * MB);
  u16* hid   = (u16*)(ws + 66 * MB);
  float* madd = (float*)(ws + 74 * MB);

  cvt_acts<<<8192, 256, 0, stream>>>(q, k, v, kb, qbf, kbf, vbf, kbbf);
  cvt_wts<<<2560, 256, 0, stream>>>(Wq, Wk, Wv, Wkb, Wo, Wqbf, Wkbf, Wvbf, Wkbbf, Wobf);
  mk_madd<<<16, 256, 0, stream>>>(mask, madd);
  gemm_nt<1, 0><<<512, 256, 0, stream>>>(qbf, Wqbf, nullptr, nullptr, bq, nullptr, Qp);
  gemm_nt<2, 0><<<512, 256, 0, stream>>>(kbf, Wkbf, kbbf, Wkbbf, bk, bkb, KKp);
  gemm_nt<1, 1><<<512, 256, 0, stream>>>(vbf, Wvbf, nullptr, nullptr, bv, nullptr, Vtp);
  attn<<<1024, 256, 0, stream>>>(Qp, KKp, Vtp, madd, hid);
  gemm_nt<1, 2><<<512, 256, 0, stream>>>(hid, Wobf, nullptr, nullptr, bo, nullptr, d_out);
}

// Round 2
// 130.294 us; speedup vs baseline: 1.1668x; 1.1668x over previous
//
#include <hip/hip_runtime.h>
#include <hip/hip_bf16.h>
#include <stdint.h>

#define B_   4
#define S_   1024
#define HID_ 1024
#define H_   16
#define DH_  64

typedef short bf16x8 __attribute__((ext_vector_type(8)));
typedef float f32x4  __attribute__((ext_vector_type(4)));
typedef unsigned int u32;
typedef unsigned short u16;

typedef u32 __attribute__((address_space(1))) as1_u32;
typedef u32 __attribute__((address_space(3))) as3_u32;

__device__ __forceinline__ f32x4 mfma16(bf16x8 a, bf16x8 b, f32x4 c) {
  return __builtin_amdgcn_mfma_f32_16x16x32_bf16(a, b, c, 0, 0, 0);
}

__device__ __forceinline__ void gload16(const void* g, void* l) {
  __builtin_amdgcn_global_load_lds((const as1_u32*)g, (as3_u32*)l, 16, 0, 0);
}

__device__ __forceinline__ u16 f2bf(float f) {
  __hip_bfloat16 h = __float2bfloat16(f);
  union { __hip_bfloat16 h; u16 u; } cv; cv.h = h; return cv.u;
}

__device__ __forceinline__ u32 cvtpk(float lo, float hi) {
  u32 r;
  asm("v_cvt_pk_bf16_f32 %0, %1, %2" : "=v"(r) : "v"(lo), "v"(hi));
  return r;
}

// ---------------- converts ----------------
__global__ __launch_bounds__(256) void cvt_acts(const float* a0, const float* a1,
                                                const float* a2, const float* a3,
                                                u16* d0, u16* d1, u16* d2, u16* d3) {
  int t = blockIdx.x * 256 + threadIdx.x;
  int sel = t >> 19;
  size_t i = (size_t)(t & 524287) * 8;
  const float* s; u16* d;
  if (sel == 0)      { s = a0; d = d0; }
  else if (sel == 1) { s = a1; d = d1; }
  else if (sel == 2) { s = a2; d = d2; }
  else               { s = a3; d = d3; }
  float4 v0 = *(const float4*)(s + i);
  float4 v1 = *(const float4*)(s + i + 4);
  uint4 r;
  r.x = (u32)f2bf(v0.x) | ((u32)f2bf(v0.y) << 16);
  r.y = (u32)f2bf(v0.z) | ((u32)f2bf(v0.w) << 16);
  r.z = (u32)f2bf(v1.x) | ((u32)f2bf(v1.y) << 16);
  r.w = (u32)f2bf(v1.z) | ((u32)f2bf(v1.w) << 16);
  *(uint4*)(d + i) = r;
}

__global__ __launch_bounds__(256) void cvt_wts(const float* a0, const float* a1,
                                               const float* a2, const float* a3, const float* a4,
                                               u16* d0, u16* d1, u16* d2, u16* d3, u16* d4) {
  int t = blockIdx.x * 256 + threadIdx.x;
  int sel = t >> 17;
  size_t i = (size_t)(t & 131071) * 8;
  const float* s; u16* d;
  if (sel == 0)      { s = a0; d = d0; }
  else if (sel == 1) { s = a1; d = d1; }
  else if (sel == 2) { s = a2; d = d2; }
  else if (sel == 3) { s = a3; d = d3; }
  else               { s = a4; d = d4; }
  float4 v0 = *(const float4*)(s + i);
  float4 v1 = *(const float4*)(s + i + 4);
  uint4 r;
  r.x = (u32)f2bf(v0.x) | ((u32)f2bf(v0.y) << 16);
  r.y = (u32)f2bf(v0.z) | ((u32)f2bf(v0.w) << 16);
  r.z = (u32)f2bf(v1.x) | ((u32)f2bf(v1.y) << 16);
  r.w = (u32)f2bf(v1.z) | ((u32)f2bf(v1.w) << 16);
  *(uint4*)(d + i) = r;
}

// ---------------- batched projection GEMM: 128x128 tile, m97 structure ----------------
// grid 768: unit = bid>>8 (0: KK K=2048, 1: Q (scaled), 2: V transposed-out)
// 256 threads = 4 waves (2x2), each wave 64x64 output, BK=64.
__global__ __launch_bounds__(256) void gemm_proj(
    const u16* __restrict__ qbf, const u16* __restrict__ Wqbf,
    const u16* __restrict__ kbf, const u16* __restrict__ Wkbf,
    const u16* __restrict__ kbbf, const u16* __restrict__ Wkbbf,
    const u16* __restrict__ vbf, const u16* __restrict__ Wvbf,
    const float* __restrict__ bq, const float* __restrict__ bk,
    const float* __restrict__ bkb, const float* __restrict__ bv,
    u16* __restrict__ Qp, u16* __restrict__ KKp, u16* __restrict__ Vtp) {
  __shared__ __align__(16) char smem[32768];   // A tile 16KB @0, W tile 16KB @16384
  const int tid = threadIdx.x;
  const int lane = tid & 63, w = tid >> 6;
  const int g = lane >> 4, ql = lane & 15;
  const int wm = w >> 1, wn = w & 1;
  const int unit = blockIdx.x >> 8;
  const int bidu = blockIdx.x & 255;
  const int m0 = (bidu >> 3) * 128;
  const int n0 = (bidu & 7) * 128;
  const int xr = ql & 7;

  const u16 *A0, *W0, *A1, *W1;
  const float *b0, *b1;
  int nkt; float osc;
  if (unit == 0) { A0 = kbf; W0 = Wkbf; A1 = kbbf; W1 = Wkbbf; b0 = bk; b1 = bkb; nkt = 32; osc = 1.f; }
  else if (unit == 1) { A0 = qbf; W0 = Wqbf; A1 = qbf; W1 = Wqbf; b0 = bq; b1 = nullptr; nkt = 16;
                        osc = 0.07216878364870322f * 1.44269504088896340f; }
  else { A0 = vbf; W0 = Wvbf; A1 = vbf; W1 = Wvbf; b0 = bv; b1 = nullptr; nkt = 16; osc = 1.f; }

  f32x4 acc[4][4];
  #pragma unroll
  for (int mi = 0; mi < 4; ++mi)
    #pragma unroll
    for (int ni = 0; ni < 4; ++ni) acc[mi][ni] = f32x4{0.f, 0.f, 0.f, 0.f};

  for (int kt = 0; kt < nkt; ++kt) {
    const u16* As = (kt >= 16) ? A1 : A0;
    const u16* Ws = (kt >= 16) ? W1 : W0;
    const int kk = (kt & 15) * 64;
    #pragma unroll
    for (int is = 0; is < 4; ++is) {
      int o = is * 4096 + tid * 16;
      int row = o >> 7, ch = (o >> 4) & 7;
      gload16(As + (size_t)(m0 + row) * HID_ + kk + ((ch ^ (row & 7)) * 8),
              smem + is * 4096 + w * 1024);
      gload16(Ws + (size_t)(n0 + row) * HID_ + kk + ((ch ^ (row & 7)) * 8),
              smem + 16384 + is * 4096 + w * 1024);
    }
    __syncthreads();

    bf16x8 af[4][2], bfv[4][2];
    #pragma unroll
    for (int mi = 0; mi < 4; ++mi)
      #pragma unroll
      for (int c = 0; c < 2; ++c) {
        int row = wm * 64 + mi * 16 + ql;
        af[mi][c] = *(const bf16x8*)(smem + row * 128 + (((c * 4 + g) ^ xr) * 16));
      }
    #pragma unroll
    for (int ni = 0; ni < 4; ++ni)
      #pragma unroll
      for (int c = 0; c < 2; ++c) {
        int row = wn * 64 + ni * 16 + ql;
        bfv[ni][c] = *(const bf16x8*)(smem + 16384 + row * 128 + (((c * 4 + g) ^ xr) * 16));
      }
    #pragma unroll
    for (int c = 0; c < 2; ++c)
      #pragma unroll
      for (int mi = 0; mi < 4; ++mi)
        #pragma unroll
        for (int ni = 0; ni < 4; ++ni)
          acc[mi][ni] = mfma16(af[mi][c], bfv[ni][c], acc[mi][ni]);
    __syncthreads();
  }

  if (unit != 2) {
    u16* outp = (unit == 0) ? KKp : Qp;
    #pragma unroll
    for (int ni = 0; ni < 4; ++ni) {
      int n = n0 + wn * 64 + ni * 16 + ql;
      float bs = b0[n];
      if (unit == 0) bs += b1[n];
      #pragma unroll
      for (int mi = 0; mi < 4; ++mi)
        #pragma unroll
        for (int i = 0; i < 4; ++i) {
          int m = m0 + wm * 64 + mi * 16 + g * 4 + i;
          outp[(size_t)m * HID_ + n] = f2bf((acc[mi][ni][i] + bs) * osc);
        }
    }
  } else {
    // transpose epilogue: per-wave 8KB LDS region, swizzled, then 128B/lane writes
    char* tp = smem + w * 8192;
    #pragma unroll
    for (int ni = 0; ni < 4; ++ni) {
      int n = n0 + wn * 64 + ni * 16 + ql;
      float bs = b0[n];
      #pragma unroll
      for (int mi = 0; mi < 4; ++mi)
        #pragma unroll
        for (int i = 0; i < 4; ++i) {
          int nl = ni * 16 + ql;
          int ml = mi * 16 + g * 4 + i;
          *(u16*)(tp + nl * 128 + (((ml >> 3) ^ (nl & 7)) * 16) + (ml & 7) * 2) =
              f2bf(acc[mi][ni][i] + bs);
        }
    }
    __syncthreads();
    int nl = lane;
    int n = n0 + wn * 64 + nl;
    int h = n >> 6, dh = n & 63;
    int mb = m0 + wm * 64;
    int b = mb >> 10, s0 = mb & 1023;
    int bh = b * H_ + h;
    u16* orow = Vtp + (((size_t)(bh * DH_ + dh)) << 10) + s0;
    #pragma unroll
    for (int j = 0; j < 8; ++j) {
      uint4 val = *(const uint4*)(tp + nl * 128 + ((j ^ (nl & 7)) * 16));
      *(uint4*)(orow + j * 8) = val;
    }
  }
}

// ---------------- O GEMM (128x64 tile, bf16 in, f32 out) ----------------
__global__ __launch_bounds__(256) void gemm_o(const u16* __restrict__ A0, const u16* __restrict__ W0,
                                              const float* __restrict__ bias0, float* __restrict__ outp) {
  __shared__ __align__(16) char smem[24576];
  const int tid = threadIdx.x;
  const int lane = tid & 63, w = tid >> 6;
  const int g = lane >> 4, ql = lane & 15;
  const int wm = w >> 1, wn = w & 1;
  const int bid = blockIdx.x;
  const int m0 = (bid >> 4) * 128;
  const int n0 = (bid & 15) * 64;
  const int xr = ql & 7;

  f32x4 acc[4][2];
  #pragma unroll
  for (int mi = 0; mi < 4; ++mi)
    #pragma unroll
    for (int ni = 0; ni < 2; ++ni) acc[mi][ni] = f32x4{0.f, 0.f, 0.f, 0.f};

  for (int kt = 0; kt < 16; ++kt) {
    const int kk = kt * 64;
    #pragma unroll
    for (int is = 0; is < 4; ++is) {
      int o = is * 4096 + tid * 16;
      int row = o >> 7, ch = (o >> 4) & 7;
      gload16(A0 + (size_t)(m0 + row) * HID_ + kk + ((ch ^ (row & 7)) * 8),
              smem + is * 4096 + w * 1024);
    }
    #pragma unroll
    for (int is = 0; is < 2; ++is) {
      int o = is * 4096 + tid * 16;
      int row = o >> 7, ch = (o >> 4) & 7;
      gload16(W0 + (size_t)(n0 + row) * HID_ + kk + ((ch ^ (row & 7)) * 8),
              smem + 16384 + is * 4096 + w * 1024);
    }
    __syncthreads();

    bf16x8 af[4][2], bfv[2][2];
    #pragma unroll
    for (int mi = 0; mi < 4; ++mi)
      #pragma unroll
      for (int c = 0; c < 2; ++c) {
        int row = wm * 64 + mi * 16 + ql;
        af[mi][c] = *(const bf16x8*)(smem + row * 128 + (((c * 4 + g) ^ xr) * 16));
      }
    #pragma unroll
    for (int ni = 0; ni < 2; ++ni)
      #pragma unroll
      for (int c = 0; c < 2; ++c) {
        int row = wn * 32 + ni * 16 + ql;
        bfv[ni][c] = *(const bf16x8*)(smem + 16384 + row * 128 + (((c * 4 + g) ^ xr) * 16));
      }
    #pragma unroll
    for (int c = 0; c < 2; ++c)
      #pragma unroll
      for (int mi = 0; mi < 4; ++mi)
        #pragma unroll
        for (int ni = 0; ni < 2; ++ni)
          acc[mi][ni] = mfma16(af[mi][c], bfv[ni][c], acc[mi][ni]);
    __syncthreads();
  }

  #pragma unroll
  for (int ni = 0; ni < 2; ++ni) {
    int n = n0 + wn * 32 + ni * 16 + ql;
    float bs = bias0[n];
    #pragma unroll
    for (int mi = 0; mi < 4; ++mi)
      #pragma unroll
      for (int i = 0; i < 4; ++i) {
        int m = m0 + wm * 64 + mi * 16 + g * 4 + i;
        outp[(size_t)m * HID_ + n] = acc[mi][ni][i] + bs;
      }
  }
}

// ---------------- flash attention v2 ----------------
// grid 1024; XCD-grouped: bh = (bid&7)*8 + ((bid>>3)&7), qt = bid>>6 (KV of 8 bh per XCD -> 2MB, L2-fit)
// 4 waves x 16 q-rows; KV dbuf w/ early stage issue; exp2-domain softmax (Q pre-scaled by scale*log2e);
// P^T via per-wave swizzled LDS; defer-max; mask applied via cndmask from global int4.
__global__ __launch_bounds__(256, 4) void attn(const u16* __restrict__ Qp, const u16* __restrict__ KKp,
                                               const u16* __restrict__ Vt, const int* __restrict__ mask,
                                               u16* __restrict__ hidden) {
  __shared__ __align__(16) char smem[40960];   // buf0: K@0 V@8192 ; buf1: K@16384 V@24576 ; P@32768 (8KB)
  const int tid = threadIdx.x;
  const int lane = tid & 63, w = tid >> 6;
  const int g = lane >> 4, ql = lane & 15;
  const int bid = blockIdx.x;
  const int bh = (bid & 7) * 8 + ((bid >> 3) & 7);
  const int qt = bid >> 6;
  const int b = bh >> 4, h = bh & 15;
  const int q0 = qt * 64;
  const int xr = ql & 7;

  // stage iter 0 into buf0
  #pragma unroll
  for (int is = 0; is < 2; ++is) {
    int o = is * 4096 + tid * 16;
    int row = o >> 7, ch = (o >> 4) & 7;
    gload16(KKp + (size_t)(b * S_ + row) * HID_ + h * DH_ + ((ch ^ (row & 7)) * 8),
            smem + is * 4096 + w * 1024);
    gload16(Vt + (size_t)(bh * DH_ + row) * S_ + ((ch ^ (row & 7)) * 8),
            smem + 8192 + is * 4096 + w * 1024);
  }

  const u16* qrow = Qp + (size_t)(b * S_ + q0 + w * 16 + ql) * HID_ + h * DH_;
  bf16x8 qb0 = *(const bf16x8*)(qrow + g * 8);
  bf16x8 qb1 = *(const bf16x8*)(qrow + 32 + g * 8);
  const int* maskp = mask + b * S_;

  f32x4 oacc[4];
  #pragma unroll
  for (int d = 0; d < 4; ++d) oacc[d] = f32x4{0.f, 0.f, 0.f, 0.f};
  float m_run = -1e30f, l_run = 0.f;
  char* pbase = smem + 32768 + w * 2048 + ql * 128;

  __syncthreads();

  int pb = 0;
  for (int it = 0; it < 16; ++it) {
    if (it < 15) {                              // stage next tile (async, in flight during compute)
      const int k0s = (it + 1) * 64;
      const int bo = (pb ^ 1) * 16384;
      #pragma unroll
      for (int is = 0; is < 2; ++is) {
        int o = is * 4096 + tid * 16;
        int row = o >> 7, ch = (o >> 4) & 7;
        gload16(KKp + (size_t)(b * S_ + k0s + row) * HID_ + h * DH_ + ((ch ^ (row & 7)) * 8),
                smem + bo + is * 4096 + w * 1024);
        gload16(Vt + (size_t)(bh * DH_ + row) * S_ + k0s + ((ch ^ (row & 7)) * 8),
                smem + bo + 8192 + is * 4096 + w * 1024);
      }
    }
    const char* kb_ = smem + pb * 16384;
    const char* vb_ = smem + pb * 16384 + 8192;
    const int k0 = it * 64;

    float sv[4][4];
    #pragma unroll
    for (int t = 0; t < 4; ++t) {
      int4 mv = *(const int4*)(maskp + k0 + 16 * t + 4 * g);
      const char* krow = kb_ + (16 * t + ql) * 128;
      bf16x8 ka0 = *(const bf16x8*)(krow + ((g ^ xr) * 16));
      bf16x8 ka1 = *(const bf16x8*)(krow + (((4 + g) ^ xr) * 16));
      f32x4 st = mfma16(ka0, qb0, f32x4{0.f, 0.f, 0.f, 0.f});
      st = mfma16(ka1, qb1, st);
      sv[t][0] = mv.x ? st[0] : -1e9f;
      sv[t][1] = mv.y ? st[1] : -1e9f;
      sv[t][2] = mv.z ? st[2] : -1e9f;
      sv[t][3] = mv.w ? st[3] : -1e9f;
    }
    float mloc = sv[0][0];
    #pragma unroll
    for (int t = 0; t < 4; ++t)
      #pragma unroll
      for (int i = 0; i < 4; ++i) mloc = fmaxf(mloc, sv[t][i]);
    mloc = fmaxf(mloc, __shfl_xor(mloc, 16, 64));
    mloc = fmaxf(mloc, __shfl_xor(mloc, 32, 64));
    if (__any(mloc > m_run + 10.f)) {           // defer-max (exp2 domain, thr 10 -> P <= 1024)
      float mnew = fmaxf(m_run, mloc);
      float alpha = __builtin_amdgcn_exp2f(m_run - mnew);
      l_run *= alpha;
      #pragma unroll
      for (int d = 0; d < 4; ++d) oacc[d] *= alpha;
      m_run = mnew;
    }
    float rsum = 0.f;
    float pvs[4][4];
    #pragma unroll
    for (int t = 0; t < 4; ++t)
      #pragma unroll
      for (int i = 0; i < 4; ++i) {
        float p = __builtin_amdgcn_exp2f(sv[t][i] - m_run);
        pvs[t][i] = p; rsum += p;
      }
    rsum += __shfl_xor(rsum, 16, 64);
    rsum += __shfl_xor(rsum, 32, 64);
    l_run += rsum;

    // P -> per-wave LDS (swizzled b64 writes), then b128 B-frag reads
    #pragma unroll
    for (int t = 0; t < 4; ++t) {
      uint2 pw;
      pw.x = cvtpk(pvs[t][0], pvs[t][1]);
      pw.y = cvtpk(pvs[t][2], pvs[t][3]);
      *(uint2*)(pbase + (((4 * t + g) ^ (2 * xr)) * 8)) = pw;
    }
    #pragma unroll
    for (int c = 0; c < 2; ++c) {
      bf16x8 pf = *(const bf16x8*)(pbase + (((c * 4 + g) ^ xr) * 16));
      #pragma unroll
      for (int d = 0; d < 4; ++d) {
        bf16x8 va = *(const bf16x8*)(vb_ + (16 * d + ql) * 128 + (((c * 4 + g) ^ xr) * 16));
        oacc[d] = mfma16(va, pf, oacc[d]);       // out^T[dh][q]
      }
    }
    __syncthreads();
    pb ^= 1;
  }

  // epilogue: divide, LDS transpose, coalesced bf16 writes
  float inv = 1.0f / l_run;
  char* ep = smem + w * 2304;
  #pragma unroll
  for (int d = 0; d < 4; ++d)
    #pragma unroll
    for (int i = 0; i < 4; ++i)
      *(u16*)(ep + ql * 144 + (16 * d + 4 * g + i) * 2) = f2bf(oacc[d][i] * inv);
  __syncthreads();
  int r = lane >> 2, cc = lane & 3;
  const char* erow = smem + w * 2304 + r * 144 + cc * 32;
  uint4 v0 = *(const uint4*)erow;
  uint4 v1 = *(const uint4*)(erow + 16);
  u16* orow = hidden + (size_t)(b * S_ + q0 + w * 16 + r) * HID_ + h * DH_ + cc * 16;
  *(uint4*)orow = v0;
  *(uint4*)(orow + 8) = v1;
}

// ---------------- launch ----------------
extern "C" void kernel_launch(void* const* d_in, const int* in_sizes, int n_in,
                              void* d_out, int out_size, void* d_ws, size_t ws_size,
                              hipStream_t stream) {
  (void)in_sizes; (void)n_in; (void)out_size; (void)ws_size;
  const float* q    = (const float*)d_in[0];
  const float* k    = (const float*)d_in[1];
  const float* v    = (const float*)d_in[2];
  const float* kb   = (const float*)d_in[3];
  const int*   mask = (const int*)  d_in[4];
  const float* Wq   = (const float*)d_in[5];
  const float* bq   = (const float*)d_in[6];
  const float* Wk   = (const float*)d_in[7];
  const float* bk   = (const float*)d_in[8];
  const float* Wv   = (const float*)d_in[9];
  const float* bv   = (const float*)d_in[10];
  const float* Wkb  = (const float*)d_in[11];
  const float* bkb  = (const float*)d_in[12];
  const float* Wo   = (const float*)d_in[13];
  const float* bo   = (const float*)d_in[14];

  char* ws = (char*)d_ws;
  const size_t MB = 1024 * 1024;
  u16* qbf   = (u16*)(ws + 0 * MB);
  u16* kbf   = (u16*)(ws + 8 * MB);
  u16* vbf   = (u16*)(ws + 16 * MB);
  u16* kbbf  = (u16*)(ws + 24 * MB);
  u16* Wqbf  = (u16*)(ws + 32 * MB);
  u16* Wkbf  = (u16*)(ws + 34 * MB);
  u16* Wvbf  = (u16*)(ws + 36 * MB);
  u16* Wkbbf = (u16*)(ws + 38 * MB);
  u16* Wobf  = (u16*)(ws + 40 * MB);
  u16* Qp    = (u16*)(ws + 42 * MB);
  u16* KKp   = (u16*)(ws + 50 * MB);
  u16* Vtp   = (u16*)(ws + 58 * MB);
  u16* hid   = (u16*)(ws + 66 * MB);

  cvt_acts<<<8192, 256, 0, stream>>>(q, k, v, kb, qbf, kbf, vbf, kbbf);
  cvt_wts<<<2560, 256, 0, stream>>>(Wq, Wk, Wv, Wkb, Wo, Wqbf, Wkbf, Wvbf, Wkbbf, Wobf);
  gemm_proj<<<768, 256, 0, stream>>>(qbf, Wqbf, kbf, Wkbf, kbbf, Wkbbf, vbf, Wvbf,
                                     bq, bk, bkb, bv, Qp, KKp, Vtp);
  attn<<<1024, 256, 0, stream>>>(Qp, KKp, Vtp, mask, hid);
  gemm_o<<<512, 256, 0, stream>>>(hid, Wobf, bo, (float*)d_out);
}

// Round 3
// 127.157 us; speedup vs baseline: 1.1956x; 1.0247x over previous
//
#include <hip/hip_runtime.h>
#include <hip/hip_bf16.h>
#include <stdint.h>

#define B_   4
#define S_   1024
#define HID_ 1024
#define H_   16
#define DH_  64

typedef short bf16x8 __attribute__((ext_vector_type(8)));
typedef float f32x4  __attribute__((ext_vector_type(4)));
typedef unsigned int u32;
typedef unsigned short u16;

typedef u32 __attribute__((address_space(1))) as1_u32;
typedef u32 __attribute__((address_space(3))) as3_u32;

__device__ __forceinline__ f32x4 mfma16(bf16x8 a, bf16x8 b, f32x4 c) {
  return __builtin_amdgcn_mfma_f32_16x16x32_bf16(a, b, c, 0, 0, 0);
}

__device__ __forceinline__ void gload16(const void* g, void* l) {
  __builtin_amdgcn_global_load_lds((const as1_u32*)g, (as3_u32*)l, 16, 0, 0);
}

__device__ __forceinline__ u16 f2bf(float f) {
  __hip_bfloat16 h = __float2bfloat16(f);
  union { __hip_bfloat16 h; u16 u; } cv; cv.h = h; return cv.u;
}

__device__ __forceinline__ u32 cvtpk(float lo, float hi) {
  u32 r;
  asm("v_cvt_pk_bf16_f32 %0, %1, %2" : "=v"(r) : "v"(lo), "v"(hi));
  return r;
}

// ---------------- fused converts (acts + weights) ----------------
__global__ __launch_bounds__(256) void cvt_all(
    const float* a0, const float* a1, const float* a2, const float* a3,
    const float* w0, const float* w1, const float* w2, const float* w3, const float* w4,
    u16* da0, u16* da1, u16* da2, u16* da3,
    u16* dw0, u16* dw1, u16* dw2, u16* dw3, u16* dw4) {
  int bb = blockIdx.x;
  const float* s; u16* d; size_t i;
  if (bb < 8192) {
    int t = bb * 256 + threadIdx.x;
    int sel = t >> 19;
    i = (size_t)(t & 524287) * 8;
    if (sel == 0)      { s = a0; d = da0; }
    else if (sel == 1) { s = a1; d = da1; }
    else if (sel == 2) { s = a2; d = da2; }
    else               { s = a3; d = da3; }
  } else {
    int t = (bb - 8192) * 256 + threadIdx.x;
    int sel = t >> 17;
    i = (size_t)(t & 131071) * 8;
    if (sel == 0)      { s = w0; d = dw0; }
    else if (sel == 1) { s = w1; d = dw1; }
    else if (sel == 2) { s = w2; d = dw2; }
    else if (sel == 3) { s = w3; d = dw3; }
    else               { s = w4; d = dw4; }
  }
  float4 v0 = *(const float4*)(s + i);
  float4 v1 = *(const float4*)(s + i + 4);
  uint4 r;
  r.x = cvtpk(v0.x, v0.y);
  r.y = cvtpk(v0.z, v0.w);
  r.z = cvtpk(v1.x, v1.y);
  r.w = cvtpk(v1.z, v1.w);
  *(uint4*)(d + i) = r;
}

// ---------------- fused projection GEMM, uniform blocks ----------------
// grid 1024, XCD-chunked swizzle. logical<512: KK (128x64 tile, K=2048 over k,kb);
// 512..767: Q (128x128, scaled out); 768..1023: V (128x128, transposed out).
// All blocks: 512 MFMA. 4 blocks/CU.
__global__ __launch_bounds__(256) void gemm_proj(
    const u16* __restrict__ qbf, const u16* __restrict__ Wqbf,
    const u16* __restrict__ kbf, const u16* __restrict__ Wkbf,
    const u16* __restrict__ kbbf, const u16* __restrict__ Wkbbf,
    const u16* __restrict__ vbf, const u16* __restrict__ Wvbf,
    const float* __restrict__ bq, const float* __restrict__ bk,
    const float* __restrict__ bkb, const float* __restrict__ bv,
    u16* __restrict__ Qp, u16* __restrict__ KKp, u16* __restrict__ Vtp) {
  __shared__ __align__(16) char smem[32768];
  const int tid = threadIdx.x;
  const int lane = tid & 63, w = tid >> 6;
  const int g = lane >> 4, ql = lane & 15;
  const int wm = w >> 1, wn = w & 1;
  const int xr = ql & 7;
  const int logical = (blockIdx.x & 7) * 128 + (blockIdx.x >> 3);

  if (logical < 512) {
    // ---- KK: tile 128x64, K = 2048 (k then kb) ----
    const int m0 = (logical >> 4) * 128;
    const int n0 = (logical & 15) * 64;
    f32x4 acc[4][2];
    #pragma unroll
    for (int mi = 0; mi < 4; ++mi)
      #pragma unroll
      for (int ni = 0; ni < 2; ++ni) acc[mi][ni] = f32x4{0.f, 0.f, 0.f, 0.f};

    for (int kt = 0; kt < 32; ++kt) {
      const u16* As = (kt < 16) ? kbf : kbbf;
      const u16* Ws = (kt < 16) ? Wkbf : Wkbbf;
      const int kk = (kt & 15) * 64;
      #pragma unroll
      for (int is = 0; is < 4; ++is) {
        int o = is * 4096 + tid * 16;
        int row = o >> 7, ch = (o >> 4) & 7;
        gload16(As + (size_t)(m0 + row) * HID_ + kk + ((ch ^ (row & 7)) * 8),
                smem + is * 4096 + w * 1024);
      }
      #pragma unroll
      for (int is = 0; is < 2; ++is) {
        int o = is * 4096 + tid * 16;
        int row = o >> 7, ch = (o >> 4) & 7;
        gload16(Ws + (size_t)(n0 + row) * HID_ + kk + ((ch ^ (row & 7)) * 8),
                smem + 16384 + is * 4096 + w * 1024);
      }
      __syncthreads();
      bf16x8 af[4][2], bfv[2][2];
      #pragma unroll
      for (int mi = 0; mi < 4; ++mi)
        #pragma unroll
        for (int c = 0; c < 2; ++c) {
          int row = wm * 64 + mi * 16 + ql;
          af[mi][c] = *(const bf16x8*)(smem + row * 128 + (((c * 4 + g) ^ xr) * 16));
        }
      #pragma unroll
      for (int ni = 0; ni < 2; ++ni)
        #pragma unroll
        for (int c = 0; c < 2; ++c) {
          int row = wn * 32 + ni * 16 + ql;
          bfv[ni][c] = *(const bf16x8*)(smem + 16384 + row * 128 + (((c * 4 + g) ^ xr) * 16));
        }
      #pragma unroll
      for (int c = 0; c < 2; ++c)
        #pragma unroll
        for (int mi = 0; mi < 4; ++mi)
          #pragma unroll
          for (int ni = 0; ni < 2; ++ni)
            acc[mi][ni] = mfma16(af[mi][c], bfv[ni][c], acc[mi][ni]);
      __syncthreads();
    }
    #pragma unroll
    for (int ni = 0; ni < 2; ++ni) {
      int n = n0 + wn * 32 + ni * 16 + ql;
      float bs = bk[n] + bkb[n];
      #pragma unroll
      for (int mi = 0; mi < 4; ++mi)
        #pragma unroll
        for (int i = 0; i < 4; ++i) {
          int m = m0 + wm * 64 + mi * 16 + g * 4 + i;
          KKp[(size_t)m * HID_ + n] = f2bf(acc[mi][ni][i] + bs);
        }
    }
    return;
  }

  // ---- Q / V: tile 128x128, K = 1024 ----
  const int unit = (logical - 512) >> 8;       // 0 = Q, 1 = V
  const int bidu = logical & 255;
  const int m0 = (bidu >> 3) * 128;
  const int n0 = (bidu & 7) * 128;
  const u16* A0 = unit ? vbf : qbf;
  const u16* W0 = unit ? Wvbf : Wqbf;
  const float* b0 = unit ? bv : bq;
  const float osc = unit ? 1.f : 0.07216878364870322f * 1.44269504088896340f;

  f32x4 acc[4][4];
  #pragma unroll
  for (int mi = 0; mi < 4; ++mi)
    #pragma unroll
    for (int ni = 0; ni < 4; ++ni) acc[mi][ni] = f32x4{0.f, 0.f, 0.f, 0.f};

  for (int kt = 0; kt < 16; ++kt) {
    const int kk = kt * 64;
    #pragma unroll
    for (int is = 0; is < 4; ++is) {
      int o = is * 4096 + tid * 16;
      int row = o >> 7, ch = (o >> 4) & 7;
      gload16(A0 + (size_t)(m0 + row) * HID_ + kk + ((ch ^ (row & 7)) * 8),
              smem + is * 4096 + w * 1024);
      gload16(W0 + (size_t)(n0 + row) * HID_ + kk + ((ch ^ (row & 7)) * 8),
              smem + 16384 + is * 4096 + w * 1024);
    }
    __syncthreads();
    bf16x8 af[4][2], bfv[4][2];
    #pragma unroll
    for (int mi = 0; mi < 4; ++mi)
      #pragma unroll
      for (int c = 0; c < 2; ++c) {
        int row = wm * 64 + mi * 16 + ql;
        af[mi][c] = *(const bf16x8*)(smem + row * 128 + (((c * 4 + g) ^ xr) * 16));
      }
    #pragma unroll
    for (int ni = 0; ni < 4; ++ni)
      #pragma unroll
      for (int c = 0; c < 2; ++c) {
        int row = wn * 64 + ni * 16 + ql;
        bfv[ni][c] = *(const bf16x8*)(smem + 16384 + row * 128 + (((c * 4 + g) ^ xr) * 16));
      }
    #pragma unroll
    for (int c = 0; c < 2; ++c)
      #pragma unroll
      for (int mi = 0; mi < 4; ++mi)
        #pragma unroll
        for (int ni = 0; ni < 4; ++ni)
          acc[mi][ni] = mfma16(af[mi][c], bfv[ni][c], acc[mi][ni]);
    __syncthreads();
  }

  if (unit == 0) {
    #pragma unroll
    for (int ni = 0; ni < 4; ++ni) {
      int n = n0 + wn * 64 + ni * 16 + ql;
      float bs = b0[n];
      #pragma unroll
      for (int mi = 0; mi < 4; ++mi)
        #pragma unroll
        for (int i = 0; i < 4; ++i) {
          int m = m0 + wm * 64 + mi * 16 + g * 4 + i;
          Qp[(size_t)m * HID_ + n] = f2bf((acc[mi][ni][i] + bs) * osc);
        }
    }
  } else {
    char* tp = smem + w * 8192;
    #pragma unroll
    for (int ni = 0; ni < 4; ++ni) {
      int n = n0 + wn * 64 + ni * 16 + ql;
      float bs = b0[n];
      #pragma unroll
      for (int mi = 0; mi < 4; ++mi)
        #pragma unroll
        for (int i = 0; i < 4; ++i) {
          int nl = ni * 16 + ql;
          int ml = mi * 16 + g * 4 + i;
          *(u16*)(tp + nl * 128 + (((ml >> 3) ^ (nl & 7)) * 16) + (ml & 7) * 2) =
              f2bf(acc[mi][ni][i] + bs);
        }
    }
    __syncthreads();
    int nl = lane;
    int n = n0 + wn * 64 + nl;
    int h = n >> 6, dh = n & 63;
    int mb = m0 + wm * 64;
    int b = mb >> 10, s0 = mb & 1023;
    int bh = b * H_ + h;
    u16* orow = Vtp + (((size_t)(bh * DH_ + dh)) << 10) + s0;
    #pragma unroll
    for (int j = 0; j < 8; ++j) {
      uint4 val = *(const uint4*)(tp + nl * 128 + ((j ^ (nl & 7)) * 16));
      *(uint4*)(orow + j * 8) = val;
    }
  }
}

// ---------------- O GEMM (128x64 tile, bf16 in, f32 out) ----------------
__global__ __launch_bounds__(256) void gemm_o(const u16* __restrict__ A0, const u16* __restrict__ W0,
                                              const float* __restrict__ bias0, float* __restrict__ outp) {
  __shared__ __align__(16) char smem[24576];
  const int tid = threadIdx.x;
  const int lane = tid & 63, w = tid >> 6;
  const int g = lane >> 4, ql = lane & 15;
  const int wm = w >> 1, wn = w & 1;
  const int logical = (blockIdx.x & 7) * 64 + (blockIdx.x >> 3);
  const int m0 = (logical >> 4) * 128;
  const int n0 = (logical & 15) * 64;
  const int xr = ql & 7;

  f32x4 acc[4][2];
  #pragma unroll
  for (int mi = 0; mi < 4; ++mi)
    #pragma unroll
    for (int ni = 0; ni < 2; ++ni) acc[mi][ni] = f32x4{0.f, 0.f, 0.f, 0.f};

  for (int kt = 0; kt < 16; ++kt) {
    const int kk = kt * 64;
    #pragma unroll
    for (int is = 0; is < 4; ++is) {
      int o = is * 4096 + tid * 16;
      int row = o >> 7, ch = (o >> 4) & 7;
      gload16(A0 + (size_t)(m0 + row) * HID_ + kk + ((ch ^ (row & 7)) * 8),
              smem + is * 4096 + w * 1024);
    }
    #pragma unroll
    for (int is = 0; is < 2; ++is) {
      int o = is * 4096 + tid * 16;
      int row = o >> 7, ch = (o >> 4) & 7;
      gload16(W0 + (size_t)(n0 + row) * HID_ + kk + ((ch ^ (row & 7)) * 8),
              smem + 16384 + is * 4096 + w * 1024);
    }
    __syncthreads();
    bf16x8 af[4][2], bfv[2][2];
    #pragma unroll
    for (int mi = 0; mi < 4; ++mi)
      #pragma unroll
      for (int c = 0; c < 2; ++c) {
        int row = wm * 64 + mi * 16 + ql;
        af[mi][c] = *(const bf16x8*)(smem + row * 128 + (((c * 4 + g) ^ xr) * 16));
      }
    #pragma unroll
    for (int ni = 0; ni < 2; ++ni)
      #pragma unroll
      for (int c = 0; c < 2; ++c) {
        int row = wn * 32 + ni * 16 + ql;
        bfv[ni][c] = *(const bf16x8*)(smem + 16384 + row * 128 + (((c * 4 + g) ^ xr) * 16));
      }
    #pragma unroll
    for (int c = 0; c < 2; ++c)
      #pragma unroll
      for (int mi = 0; mi < 4; ++mi)
        #pragma unroll
        for (int ni = 0; ni < 2; ++ni)
          acc[mi][ni] = mfma16(af[mi][c], bfv[ni][c], acc[mi][ni]);
    __syncthreads();
  }

  #pragma unroll
  for (int ni = 0; ni < 2; ++ni) {
    int n = n0 + wn * 32 + ni * 16 + ql;
    float bs = bias0[n];
    #pragma unroll
    for (int mi = 0; mi < 4; ++mi)
      #pragma unroll
      for (int i = 0; i < 4; ++i) {
        int m = m0 + wm * 64 + mi * 16 + g * 4 + i;
        outp[(size_t)m * HID_ + n] = acc[mi][ni][i] + bs;
      }
  }
}

// ---------------- flash attention v3 (counted vmcnt, no barrier drain) ----------------
__global__ __launch_bounds__(256, 4) void attn(const u16* __restrict__ Qp, const u16* __restrict__ KKp,
                                               const u16* __restrict__ Vt, const int* __restrict__ mask,
                                               u16* __restrict__ hidden) {
  __shared__ __align__(16) char smem[40960];   // buf0 K@0 V@8192; buf1 K@16384 V@24576; P@32768
  const int tid = threadIdx.x;
  const int lane = tid & 63, w = tid >> 6;
  const int g = lane >> 4, ql = lane & 15;
  const int bid = blockIdx.x;
  const int bh = (bid & 7) * 8 + ((bid >> 3) & 7);
  const int qt = bid >> 6;
  const int b = bh >> 4, h = bh & 15;
  const int q0 = qt * 64;
  const int xr = ql & 7;

  // stage iter 0 into buf0 (4 gload_lds)
  #pragma unroll
  for (int is = 0; is < 2; ++is) {
    int o = is * 4096 + tid * 16;
    int row = o >> 7, ch = (o >> 4) & 7;
    gload16(KKp + (size_t)(b * S_ + row) * HID_ + h * DH_ + ((ch ^ (row & 7)) * 8),
            smem + is * 4096 + w * 1024);
    gload16(Vt + (size_t)(bh * DH_ + row) * S_ + ((ch ^ (row & 7)) * 8),
            smem + 8192 + is * 4096 + w * 1024);
  }

  const u16* qrow = Qp + (size_t)(b * S_ + q0 + w * 16 + ql) * HID_ + h * DH_;
  bf16x8 qb0 = *(const bf16x8*)(qrow + g * 8);
  bf16x8 qb1 = *(const bf16x8*)(qrow + 32 + g * 8);
  const int* maskp = mask + b * S_;

  f32x4 oacc[4];
  #pragma unroll
  for (int d = 0; d < 4; ++d) oacc[d] = f32x4{0.f, 0.f, 0.f, 0.f};
  float m_run = -1e30f, l_run = 0.f;
  char* pbase = smem + 32768 + w * 2048 + ql * 128;

  int pb = 0;
  for (int it = 0; it < 16; ++it) {
    const int k0 = it * 64;
    // current-iter mask loads FIRST (so compiler's mask-wait is vmcnt(4), not a drain)
    int4 mv[4];
    #pragma unroll
    for (int t = 0; t < 4; ++t) mv[t] = *(const int4*)(maskp + k0 + 16 * t + 4 * g);
    __builtin_amdgcn_sched_barrier(0);
    if (it < 15) {
      const int k0s = k0 + 64;
      const int bo = (pb ^ 1) * 16384;
      #pragma unroll
      for (int is = 0; is < 2; ++is) {
        int o = is * 4096 + tid * 16;
        int row = o >> 7, ch = (o >> 4) & 7;
        gload16(KKp + (size_t)(b * S_ + k0s + row) * HID_ + h * DH_ + ((ch ^ (row & 7)) * 8),
                smem + bo + is * 4096 + w * 1024);
        gload16(Vt + (size_t)(bh * DH_ + row) * S_ + k0s + ((ch ^ (row & 7)) * 8),
                smem + bo + 8192 + is * 4096 + w * 1024);
      }
      asm volatile("s_waitcnt vmcnt(4)" ::: "memory");
    } else {
      asm volatile("s_waitcnt vmcnt(0)" ::: "memory");
    }
    __builtin_amdgcn_s_barrier();

    const char* kb_ = smem + pb * 16384;
    const char* vb_ = smem + pb * 16384 + 8192;

    float sv[4][4];
    #pragma unroll
    for (int t = 0; t < 4; ++t) {
      const char* krow = kb_ + (16 * t + ql) * 128;
      bf16x8 ka0 = *(const bf16x8*)(krow + ((g ^ xr) * 16));
      bf16x8 ka1 = *(const bf16x8*)(krow + (((4 + g) ^ xr) * 16));
      f32x4 st = mfma16(ka0, qb0, f32x4{0.f, 0.f, 0.f, 0.f});
      st = mfma16(ka1, qb1, st);
      sv[t][0] = mv[t].x ? st[0] : -1e9f;
      sv[t][1] = mv[t].y ? st[1] : -1e9f;
      sv[t][2] = mv[t].z ? st[2] : -1e9f;
      sv[t][3] = mv[t].w ? st[3] : -1e9f;
    }
    float mloc = sv[0][0];
    #pragma unroll
    for (int t = 0; t < 4; ++t)
      #pragma unroll
      for (int i = 0; i < 4; ++i) mloc = fmaxf(mloc, sv[t][i]);
    mloc = fmaxf(mloc, __shfl_xor(mloc, 16, 64));
    mloc = fmaxf(mloc, __shfl_xor(mloc, 32, 64));
    if (__any(mloc > m_run + 10.f)) {
      float mnew = fmaxf(m_run, mloc);
      float alpha = __builtin_amdgcn_exp2f(m_run - mnew);
      l_run *= alpha;
      #pragma unroll
      for (int d = 0; d < 4; ++d) oacc[d] *= alpha;
      m_run = mnew;
    }
    float rsum = 0.f;
    float pvs[4][4];
    #pragma unroll
    for (int t = 0; t < 4; ++t)
      #pragma unroll
      for (int i = 0; i < 4; ++i) {
        float p = __builtin_amdgcn_exp2f(sv[t][i] - m_run);
        pvs[t][i] = p; rsum += p;
      }
    rsum += __shfl_xor(rsum, 16, 64);
    rsum += __shfl_xor(rsum, 32, 64);
    l_run += rsum;

    #pragma unroll
    for (int t = 0; t < 4; ++t) {
      uint2 pw;
      pw.x = cvtpk(pvs[t][0], pvs[t][1]);
      pw.y = cvtpk(pvs[t][2], pvs[t][3]);
      *(uint2*)(pbase + (((4 * t + g) ^ (2 * xr)) * 8)) = pw;
    }
    #pragma unroll
    for (int c = 0; c < 2; ++c) {
      bf16x8 pf = *(const bf16x8*)(pbase + (((c * 4 + g) ^ xr) * 16));
      #pragma unroll
      for (int d = 0; d < 4; ++d) {
        bf16x8 va = *(const bf16x8*)(vb_ + (16 * d + ql) * 128 + (((c * 4 + g) ^ xr) * 16));
        oacc[d] = mfma16(va, pf, oacc[d]);
      }
    }
    __builtin_amdgcn_s_barrier();
    pb ^= 1;
  }

  float inv = 1.0f / l_run;
  char* ep = smem + w * 2304;
  #pragma unroll
  for (int d = 0; d < 4; ++d)
    #pragma unroll
    for (int i = 0; i < 4; ++i)
      *(u16*)(ep + ql * 144 + (16 * d + 4 * g + i) * 2) = f2bf(oacc[d][i] * inv);
  __syncthreads();
  int r = lane >> 2, cc = lane & 3;
  const char* erow = smem + w * 2304 + r * 144 + cc * 32;
  uint4 v0 = *(const uint4*)erow;
  uint4 v1 = *(const uint4*)(erow + 16);
  u16* orow = hidden + (size_t)(b * S_ + q0 + w * 16 + r) * HID_ + h * DH_ + cc * 16;
  *(uint4*)orow = v0;
  *(uint4*)(orow + 8) = v1;
}

// ---------------- launch ----------------
extern "C" void kernel_launch(void* const* d_in, const int* in_sizes, int n_in,
                              void* d_out, int out_size, void* d_ws, size_t ws_size,
                              hipStream_t stream) {
  (void)in_sizes; (void)n_in; (void)out_size; (void)ws_size;
  const float* q    = (const float*)d_in[0];
  const float* k    = (const float*)d_in[1];
  const float* v    = (const float*)d_in[2];
  const float* kb   = (const float*)d_in[3];
  const int*   mask = (const int*)  d_in[4];
  const float* Wq   = (const float*)d_in[5];
  const float* bq   = (const float*)d_in[6];
  const float* Wk   = (const float*)d_in[7];
  const float* bk   = (const float*)d_in[8];
  const float* Wv   = (const float*)d_in[9];
  const float* bv   = (const float*)d_in[10];
  const float* Wkb  = (const float*)d_in[11];
  const float* bkb  = (const float*)d_in[12];
  const float* Wo   = (const float*)d_in[13];
  const float* bo   = (const float*)d_in[14];

  char* ws = (char*)d_ws;
  const size_t MB = 1024 * 1024;
  u16* qbf   = (u16*)(ws + 0 * MB);
  u16* kbf   = (u16*)(ws + 8 * MB);
  u16* vbf   = (u16*)(ws + 16 * MB);
  u16* kbbf  = (u16*)(ws + 24 * MB);
  u16* Wqbf  = (u16*)(ws + 32 * MB);
  u16* Wkbf  = (u16*)(ws + 34 * MB);
  u16* Wvbf  = (u16*)(ws + 36 * MB);
  u16* Wkbbf = (u16*)(ws + 38 * MB);
  u16* Wobf  = (u16*)(ws + 40 * MB);
  u16* Qp    = (u16*)(ws + 42 * MB);
  u16* KKp   = (u16*)(ws + 50 * MB);
  u16* Vtp   = (u16*)(ws + 58 * MB);
  u16* hid   = (u16*)(ws + 66 * MB);

  cvt_all<<<10752, 256, 0, stream>>>(q, k, v, kb, Wq, Wk, Wv, Wkb, Wo,
                                     qbf, kbf, vbf, kbbf, Wqbf, Wkbf, Wvbf, Wkbbf, Wobf);
  gemm_proj<<<1024, 256, 0, stream>>>(qbf, Wqbf, kbf, Wkbf, kbbf, Wkbbf, vbf, Wvbf,
                                      bq, bk, bkb, bv, Qp, KKp, Vtp);
  attn<<<1024, 256, 0, stream>>>(Qp, KKp, Vtp, mask, hid);
  gemm_o<<<512, 256, 0, stream>>>(hid, Wobf, bo, (float*)d_out);
}